// Round 15
// baseline (68.207 us; speedup 1.0000x reference)
//
#include <hip/hip_runtime.h>
#include <hip/hip_fp8.h>

#define N_NODES 100000
#define N_EDGES 1250000
#define IN_CH 64
#define HID 128
#define OUT_CH 2
#define NUM_GRAPHS 128

#define PSHIFT 8
#define PSIZE 256                               // nodes per partition
#define NPART ((N_NODES + PSIZE - 1) / PSIZE)   // 391
#define MAXE 4096   // capacity per partition region (mean 3197, sigma 56 -> 16-sigma)
#define TILE 8192   // edges per part_k block
#define PART_BLOCKS ((N_EDGES + TILE - 1) / TILE)  // 153

typedef _Float16 half2v __attribute__((ext_vector_type(2)));
typedef _Float16 half8 __attribute__((ext_vector_type(8)));
typedef float f32x4 __attribute__((ext_vector_type(4)));
typedef float f32x2 __attribute__((ext_vector_type(2)));

#define AS1 __attribute__((address_space(1)))
#define AS3 __attribute__((address_space(3)))

#define NU (N_NODES * IN_CH / 4)                  // 1.6M float4 units
#define XCAST_BLOCKS ((NU + 1023) / 1024)         // 1563 (4 float4/thread)
#define WPREP_BLOCKS 8
#define ZERO_BLOCKS 4
// zero region (u32 words): gmax | gcursor
#define ZW_GMAX (NUM_GRAPHS * HID)  // 16384
#define ZW_CUR 512
#define ZWORDS (ZW_GMAX + ZW_CUR)

__device__ __forceinline__ unsigned pkh2(float a, float b) {
    half2v h;
    h[0] = (_Float16)a;
    h[1] = (_Float16)b;
    return __builtin_bit_cast(unsigned, h);
}

// ---- fp8 e4m3 pack/unpack (HW cvt on gfx950; header-type fallback) --------
__device__ __forceinline__ unsigned pk_fp8x4(float a, float b, float c, float d) {
#if __has_builtin(__builtin_amdgcn_cvt_pk_fp8_f32)
    int r = __builtin_amdgcn_cvt_pk_fp8_f32(a, b, 0, false);
    r = __builtin_amdgcn_cvt_pk_fp8_f32(c, d, r, true);
    return (unsigned)r;
#else
    __hip_fp8_e4m3 qa(a), qb(b), qc(c), qd(d);
    return (unsigned)qa.__x | ((unsigned)qb.__x << 8) | ((unsigned)qc.__x << 16) |
           ((unsigned)qd.__x << 24);
#endif
}

__device__ __forceinline__ void dec_fp8x4(float* a, unsigned u) {
#if __has_builtin(__builtin_amdgcn_cvt_pk_f32_fp8)
    const f32x2 lo = __builtin_amdgcn_cvt_pk_f32_fp8((int)u, false);
    const f32x2 hi = __builtin_amdgcn_cvt_pk_f32_fp8((int)u, true);
    a[0] += lo[0]; a[1] += lo[1]; a[2] += hi[0]; a[3] += hi[1];
#else
    __hip_fp8_e4m3 t0, t1, t2, t3;
    t0.__x = (unsigned char)u;
    t1.__x = (unsigned char)(u >> 8);
    t2.__x = (unsigned char)(u >> 16);
    t3.__x = (unsigned char)(u >> 24);
    a[0] += (float)t0; a[1] += (float)t1; a[2] += (float)t2; a[3] += (float)t3;
#endif
}

__device__ __forceinline__ void acc16p8(float* a, uint4 v) {
    dec_fp8x4(a + 0, v.x);
    dec_fp8x4(a + 4, v.y);
    dec_fp8x4(a + 8, v.z);
    dec_fp8x4(a + 12, v.w);
}

// ---------------------------------------------------------------------------
// K1 prep: [0,XCAST) x -> {f16, fp8} with 4 float4/thread (4 loads in
// flight, 64B read + 48B written per thread); [XCAST,+WPREP) grid-stride
// weight prep; [+WPREP,+ZERO) zero gmax/gcursor.
// ---------------------------------------------------------------------------
__global__ __launch_bounds__(256) void prep_k(const float* __restrict__ x,
                                              const float* __restrict__ W_l,
                                              const float* __restrict__ W_r,
                                              unsigned short* __restrict__ xh,
                                              unsigned char* __restrict__ xh8,
                                              unsigned short* __restrict__ Wc,
                                              unsigned* __restrict__ zbase) {
    const int b = (int)blockIdx.x;
    const int tid = (int)threadIdx.x;
    if (b < XCAST_BLOCKS) {
        const int u0 = (b * 256 + tid) * 4;  // 4 consecutive float4 units
        if (u0 >= NU) return;                // NU % 4 == 0: all-or-nothing
        const float4 v0 = reinterpret_cast<const float4*>(x)[u0];
        const float4 v1 = reinterpret_cast<const float4*>(x)[u0 + 1];
        const float4 v2 = reinterpret_cast<const float4*>(x)[u0 + 2];
        const float4 v3 = reinterpret_cast<const float4*>(x)[u0 + 3];
        uint4 h0, h1;
        h0.x = pkh2(v0.x, v0.y); h0.y = pkh2(v0.z, v0.w);
        h0.z = pkh2(v1.x, v1.y); h0.w = pkh2(v1.z, v1.w);
        h1.x = pkh2(v2.x, v2.y); h1.y = pkh2(v2.z, v2.w);
        h1.z = pkh2(v3.x, v3.y); h1.w = pkh2(v3.z, v3.w);
        reinterpret_cast<uint4*>(xh)[(u0 >> 1) + 0] = h0;
        reinterpret_cast<uint4*>(xh)[(u0 >> 1) + 1] = h1;
        uint4 q;
        q.x = pk_fp8x4(v0.x, v0.y, v0.z, v0.w);
        q.y = pk_fp8x4(v1.x, v1.y, v1.z, v1.w);
        q.z = pk_fp8x4(v2.x, v2.y, v2.z, v2.w);
        q.w = pk_fp8x4(v3.x, v3.y, v3.z, v3.w);
        reinterpret_cast<uint4*>(xh8)[u0 >> 2] = q;
        return;
    }
    const int b2 = b - XCAST_BLOCKS;
    if (b2 < WPREP_BLOCKS) {
        for (int i = b2 * 256 + tid; i < HID * 2 * IN_CH; i += WPREP_BLOCKS * 256) {
            const int o = i >> 7;
            const int k = i & 127;
            const float v = (k < IN_CH) ? W_l[o * IN_CH + k] : W_r[o * IN_CH + (k - IN_CH)];
            const _Float16 h = (_Float16)v;
            Wc[i] = __builtin_bit_cast(unsigned short, h);
        }
        return;
    }
    const int z = b2 - WPREP_BLOCKS;  // 0..ZERO_BLOCKS-1
    for (int i = z * 256 + tid; i < ZWORDS; i += ZERO_BLOCKS * 256) zbase[i] = 0u;
}

// ---------------------------------------------------------------------------
// K2 part: single-pass bucketing into fixed-capacity partition regions.
// TILE=8192 (16 edges/thread). Shfl-based block scan (2 barriers). One
// atomicAdd per (block,bin) -> contiguous runs of packed u32.
// ---------------------------------------------------------------------------
__global__ __launch_bounds__(512) void part_k(const int* __restrict__ ei,
                                              unsigned* __restrict__ gcursor,
                                              unsigned* __restrict__ edgesP) {
    __shared__ int lhist[512];
    __shared__ int lpre[512];
    __shared__ int gbase[512];
    __shared__ unsigned stage[TILE];        // 32KB
    __shared__ unsigned short sbin[TILE];   // 16KB
    __shared__ int wsum[8], wpre[8];

    const int tid = (int)threadIdx.x;
    const int lane = tid & 63;
    const int wv = tid >> 6;
    const int e0 = (int)blockIdx.x * TILE;
    const int nv = min(TILE, N_EDGES - e0);

    lhist[tid] = 0;
    __syncthreads();

    int esrc[16], emeta[16];
#pragma unroll
    for (int k = 0; k < 16; ++k) {
        const int e = e0 + k * 512 + tid;
        emeta[k] = -1;
        if (e < N_EDGES) {
            esrc[k] = ei[e];
            const int dst = ei[N_EDGES + e];
            const int bin = dst >> PSHIFT;               // 9 bits (<512)
            const int dl = dst & (PSIZE - 1);            // 8 bits
            const int rank = atomicAdd(&lhist[bin], 1);  // <8192: 13 bits
            emeta[k] = bin | (dl << 9) | (rank << 17);
        }
    }
    __syncthreads();

    // block-local exclusive scan: per-wave shfl inclusive + cross-wave fixup
    const int v = lhist[tid];
    int s = v;
#pragma unroll
    for (int o = 1; o < 64; o <<= 1) {
        const int t = __shfl_up(s, o, 64);
        if (lane >= o) s += t;
    }
    if (lane == 63) wsum[wv] = s;
    __syncthreads();
    if (wv == 0) {
        const int ws = (lane < 8) ? wsum[lane] : 0;
        int p = ws;
#pragma unroll
        for (int o = 1; o < 8; o <<= 1) {
            const int t = __shfl_up(p, o, 64);
            if (lane >= o) p += t;
        }
        if (lane < 8) wpre[lane] = p - ws;
    }
    __syncthreads();
    lpre[tid] = (s - v) + wpre[wv];
    if (tid < NPART) gbase[tid] = v ? (int)atomicAdd(&gcursor[tid], (unsigned)v) : 0;
    __syncthreads();

#pragma unroll
    for (int k = 0; k < 16; ++k) {
        if (emeta[k] >= 0) {
            const int bin = emeta[k] & 511;
            const int dl = (emeta[k] >> 9) & 255;
            const int rank = emeta[k] >> 17;
            const int pos = lpre[bin] + rank;
            stage[pos] = (unsigned)esrc[k] | ((unsigned)dl << 17);
            sbin[pos] = (unsigned short)bin;
        }
    }
    __syncthreads();

    for (int i = tid; i < nv; i += 512) {
        const int b = sbin[i];
        const int pos = gbase[b] + (i - lpre[b]);
        if (pos < MAXE) edgesP[(size_t)b * MAXE + pos] = stage[i];
    }
}

// ---------------------------------------------------------------------------
// K3 meanp: one block per 256-node partition. Packed edge words read ONCE
// into regs; per-dst CSR in LDS; 2 threads/dst gather fp8 rows (2x16B/row,
// 4-row unroll = 8 loads in flight). f32 accumulate, f16 out. (R10-verified)
// ---------------------------------------------------------------------------
__global__ __launch_bounds__(512) void meanp_k(const unsigned char* __restrict__ xh8,
                                               const unsigned* __restrict__ gcursor,
                                               const unsigned* __restrict__ edgesP,
                                               unsigned short* __restrict__ meanh) {
    __shared__ int ss[MAXE];               // 16KB sorted srcs
    __shared__ unsigned char dl8[MAXE];    // 4KB
    __shared__ unsigned char rk8[MAXE];    // 4KB
    __shared__ int histL[PSIZE];
    __shared__ int rowp[PSIZE];
    __shared__ int sb[2][PSIZE];

    const int tid = (int)threadIdx.x;
    const int p = (int)blockIdx.x;
    const int node0 = p << PSHIFT;
    const size_t e0 = (size_t)p * MAXE;
    const int m = min((int)gcursor[p], MAXE);

    if (tid < PSIZE) histL[tid] = 0;
    __syncthreads();

    // pass 1: read edge word once (cached in regs), local-dst + rank
    unsigned er[8];
    {
        int k = 0;
        for (int i = tid; i < m; i += 512, ++k) {
            const unsigned pr = edgesP[e0 + i];
            er[k] = pr;
            const int d = (int)((pr >> 17) & 255u);
            dl8[i] = (unsigned char)d;
            rk8[i] = (unsigned char)atomicAdd(&histL[d], 1);
        }
    }
    __syncthreads();

    if (tid < PSIZE) sb[0][tid] = histL[tid];
    __syncthreads();
    int pb = 0;
    for (int o = 1; o < PSIZE; o <<= 1) {
        if (tid < PSIZE)
            sb[pb ^ 1][tid] = sb[pb][tid] + ((tid >= o) ? sb[pb][tid - o] : 0);
        pb ^= 1;
        __syncthreads();
    }
    if (tid < PSIZE) rowp[tid] = sb[pb][tid] - histL[tid];
    __syncthreads();

    // pass 2: scatter srcs into per-dst runs (LDS only; edge word from regs)
    {
        int k = 0;
        for (int i = tid; i < m; i += 512, ++k)
            ss[rowp[dl8[i]] + rk8[i]] = (int)(er[k] & 0x1FFFFu);
    }
    __syncthreads();

    const int owner = tid >> 1;
    const int half = tid & 1;
    const int node = node0 + owner;
    if (node >= N_NODES) return;

    const int deg = histL[owner];
    const int base = rowp[owner];

    float acc[32];
#pragma unroll
    for (int i = 0; i < 32; ++i) acc[i] = 0.f;

    int j = 0;
    for (; j + 4 <= deg; j += 4) {
        const int s0 = ss[base + j];
        const int s1 = ss[base + j + 1];
        const int s2 = ss[base + j + 2];
        const int s3 = ss[base + j + 3];
        const uint4* r0 = reinterpret_cast<const uint4*>(xh8 + (size_t)s0 * IN_CH + half * 32);
        const uint4* r1 = reinterpret_cast<const uint4*>(xh8 + (size_t)s1 * IN_CH + half * 32);
        const uint4* r2 = reinterpret_cast<const uint4*>(xh8 + (size_t)s2 * IN_CH + half * 32);
        const uint4* r3 = reinterpret_cast<const uint4*>(xh8 + (size_t)s3 * IN_CH + half * 32);
        const uint4 a0 = r0[0], a1 = r0[1];
        const uint4 b0 = r1[0], b1 = r1[1];
        const uint4 c0 = r2[0], c1 = r2[1];
        const uint4 d0 = r3[0], d1 = r3[1];
        acc16p8(acc + 0, a0); acc16p8(acc + 16, a1);
        acc16p8(acc + 0, b0); acc16p8(acc + 16, b1);
        acc16p8(acc + 0, c0); acc16p8(acc + 16, c1);
        acc16p8(acc + 0, d0); acc16p8(acc + 16, d1);
    }
    for (; j < deg; ++j) {
        const int s0 = ss[base + j];
        const uint4* r0 = reinterpret_cast<const uint4*>(xh8 + (size_t)s0 * IN_CH + half * 32);
        const uint4 a0 = r0[0], a1 = r0[1];
        acc16p8(acc + 0, a0); acc16p8(acc + 16, a1);
    }

    const float rcp = 1.0f / fmaxf((float)deg, 1.0f);
    uint4 ov[4];
#pragma unroll
    for (int c = 0; c < 4; ++c) {
        ov[c].x = pkh2(acc[c * 8 + 0] * rcp, acc[c * 8 + 1] * rcp);
        ov[c].y = pkh2(acc[c * 8 + 2] * rcp, acc[c * 8 + 3] * rcp);
        ov[c].z = pkh2(acc[c * 8 + 4] * rcp, acc[c * 8 + 5] * rcp);
        ov[c].w = pkh2(acc[c * 8 + 6] * rcp, acc[c * 8 + 7] * rcp);
    }
    uint4* op = reinterpret_cast<uint4*>(meanh + (size_t)node * IN_CH + half * 32);
#pragma unroll
    for (int c = 0; c < 4; ++c) op[c] = ov[c];
}

// ---------------------------------------------------------------------------
// K4: MFMA GEMM + relu + per-graph max pool. TWO 128-node tiles per block.
// Staging via global_load_lds (async, width=16): linear LDS dest + inverse-
// swizzled per-lane global source (rule #21). (R14-verified)
// ---------------------------------------------------------------------------
#define MBLK 128

__device__ __forceinline__ void flushmax(unsigned* lmax, unsigned int* gmax,
                                         int g, int gbase, int l15,
                                         const float* rmax) {
    const int slot = g - gbase;
    if (slot < 4) {
#pragma unroll
        for (int nt = 0; nt < 8; ++nt)
            atomicMax(&lmax[slot * HID + nt * 16 + l15], __float_as_uint(rmax[nt]));
    } else {
#pragma unroll
        for (int nt = 0; nt < 8; ++nt)
            atomicMax(&gmax[(size_t)g * HID + nt * 16 + l15], __float_as_uint(rmax[nt]));
    }
}

__global__ __launch_bounds__(512) void gemm_pool_k(const unsigned short* __restrict__ xh,
                                                   const unsigned short* __restrict__ meanh,
                                                   const unsigned short* __restrict__ Wc,
                                                   const float* __restrict__ b_l,
                                                   const int* __restrict__ batch,
                                                   unsigned int* __restrict__ gmax) {
    __shared__ uint4 fe[MBLK * 16];
    __shared__ uint4 wt[HID * 16];
    __shared__ unsigned lmax[4 * HID];
    __shared__ int bt[MBLK];

    const int tid = (int)threadIdx.x;
    const int lane = tid & 63;
    const int w = tid >> 6;
    const int l15 = lane & 15, q = lane >> 4;

    // weights: async stage once, reused by both sub-tiles
#pragma unroll
    for (int t = 0; t < 4; ++t) {
        const int id = tid + t * 512;
        const int row = id >> 4, cs = id & 15;
        const int c = cs ^ (row & 7);  // inverse swizzle on the SOURCE
        __builtin_amdgcn_global_load_lds(
            (const AS1 unsigned*)(reinterpret_cast<const uint4*>(Wc) + (row * 16 + c)),
            (AS3 unsigned*)&wt[w * 64 + t * 512], 16, 0, 0);
    }

    float bias[8];
#pragma unroll
    for (int nt = 0; nt < 8; ++nt) bias[nt] = b_l[nt * 16 + l15];

#pragma unroll 1
    for (int sub = 0; sub < 2; ++sub) {
        const int nb = (int)blockIdx.x * (2 * MBLK) + sub * MBLK;
        if (nb >= N_NODES) break;
        const int nvalid = min(MBLK, N_NODES - nb);

        if (nvalid == MBLK) {
#pragma unroll
            for (int t = 0; t < 4; ++t) {
                const int id = tid + t * 512;
                const int row = id >> 4, cs = id & 15;
                const int c = cs ^ (row & 7);
                const int n = nb + row;
                const uint4* src = (c < 8)
                    ? (reinterpret_cast<const uint4*>(meanh) + ((size_t)n * 8 + c))
                    : (reinterpret_cast<const uint4*>(xh) + ((size_t)n * 8 + (c - 8)));
                __builtin_amdgcn_global_load_lds(
                    (const AS1 unsigned*)src,
                    (AS3 unsigned*)&fe[w * 64 + t * 512], 16, 0, 0);
            }
        } else {
#pragma unroll
            for (int t = 0; t < 4; ++t) {
                const int id = tid + t * 512;
                const int row = id >> 4, c = id & 15;
                const int n = nb + row;
                uint4 v = make_uint4(0u, 0u, 0u, 0u);
                if (n < N_NODES) {
                    v = (c < 8) ? reinterpret_cast<const uint4*>(meanh)[(size_t)n * 8 + c]
                                : reinterpret_cast<const uint4*>(xh)[(size_t)n * 8 + (c - 8)];
                }
                fe[row * 16 + (c ^ (row & 7))] = v;
            }
        }
        if (tid < MBLK) bt[tid] = (nb + tid < N_NODES) ? batch[nb + tid] : -1;
        lmax[tid] = 0u;  // 4*HID == 512
        __syncthreads();  // drains vmcnt -> async LDS writes complete

        f32x4 acc[8];
#pragma unroll
        for (int nt = 0; nt < 8; ++nt) acc[nt] = (f32x4){0.f, 0.f, 0.f, 0.f};

        const int arow = w * 16 + l15;
#pragma unroll
        for (int kb = 0; kb < 4; ++kb) {
            const int ac = kb * 4 + q;
            const half8 a = __builtin_bit_cast(half8, fe[arow * 16 + (ac ^ (arow & 7))]);
#pragma unroll
            for (int nt = 0; nt < 8; ++nt) {
                const int nrow = nt * 16 + l15;
                const half8 b = __builtin_bit_cast(half8, wt[nrow * 16 + (ac ^ (nrow & 7))]);
                acc[nt] = __builtin_amdgcn_mfma_f32_16x16x32_f16(a, b, acc[nt], 0, 0, 0);
            }
        }

        const int gbase = bt[0];
        const int rowb = w * 16 + q * 4;
        int curg = -1;
        float rmax[8];
#pragma unroll
        for (int nt = 0; nt < 8; ++nt) rmax[nt] = 0.f;

#pragma unroll
        for (int reg = 0; reg < 4; ++reg) {
            const int g = bt[rowb + reg];
            if (g >= 0) {
                float h[8];
#pragma unroll
                for (int nt = 0; nt < 8; ++nt) h[nt] = fmaxf(acc[nt][reg] + bias[nt], 0.f);
                if (g != curg) {
                    if (curg >= 0) flushmax(lmax, gmax, curg, gbase, l15, rmax);
                    curg = g;
#pragma unroll
                    for (int nt = 0; nt < 8; ++nt) rmax[nt] = h[nt];
                } else {
#pragma unroll
                    for (int nt = 0; nt < 8; ++nt) rmax[nt] = fmaxf(rmax[nt], h[nt]);
                }
            }
        }
        if (curg >= 0) flushmax(lmax, gmax, curg, gbase, l15, rmax);
        __syncthreads();

        int span = bt[nvalid - 1] - gbase + 1;
        if (span > 4) span = 4;
        if (tid < span * HID) {
            const unsigned v = lmax[tid];
            if (v) atomicMax(&gmax[(size_t)(gbase + (tid >> 7)) * HID + (tid & 127)], v);
        }
        __syncthreads();  // lmax/fe reads complete before next sub re-stages
    }
}

// ---------------------------------------------------------------------------
// K5: head. out[g][oc] = gmax[g].W_lin[oc] + b_lin[oc]  (float4 dot)
// ---------------------------------------------------------------------------
__global__ __launch_bounds__(256) void head_k(const unsigned int* __restrict__ gmax_u,
                                              const float* __restrict__ W_lin,
                                              const float* __restrict__ b_lin,
                                              float* __restrict__ out) {
    const int t = (int)threadIdx.x;
    const int g = t >> 1;
    const int oc = t & 1;
    const float4* gr = reinterpret_cast<const float4*>((const float*)gmax_u + (size_t)g * HID);
    const float4* wr = reinterpret_cast<const float4*>(W_lin + oc * HID);
    float acc = b_lin[oc];
#pragma unroll 8
    for (int k = 0; k < HID / 4; ++k) {
        const float4 a = gr[k];
        const float4 w = wr[k];
        acc += a.x * w.x + a.y * w.y + a.z * w.z + a.w * w.w;
    }
    out[(size_t)g * OUT_CH + oc] = acc;
}

extern "C" void kernel_launch(void* const* d_in, const int* in_sizes, int n_in,
                              void* d_out, int out_size, void* d_ws, size_t ws_size,
                              hipStream_t stream) {
    const float* x = (const float*)d_in[0];
    const float* W_l = (const float*)d_in[1];
    const float* b_l = (const float*)d_in[2];
    const float* W_r = (const float*)d_in[3];
    const float* W_lin = (const float*)d_in[4];
    const float* b_lin = (const float*)d_in[5];
    const int* ei = (const int*)d_in[6];
    const int* batch = (const int*)d_in[7];
    float* out = (float*)d_out;

    char* ws = (char*)d_ws;
    size_t o = 0;
    unsigned* zbase = (unsigned*)(ws + o);  // gmax | gcursor (zeroed by prep)
    unsigned int* gmax = zbase;
    unsigned* gcursor = zbase + ZW_GMAX;
    o += (size_t)ZWORDS * 4;
    o = (o + 255) & ~(size_t)255;
    unsigned* edgesP = (unsigned*)(ws + o); o += (size_t)NPART * MAXE * 4;             // 6.4MB
    unsigned short* xh = (unsigned short*)(ws + o); o += (size_t)N_NODES * IN_CH * 2;  // 12.8MB
    unsigned char* xh8 = (unsigned char*)(ws + o); o += (size_t)N_NODES * IN_CH;       // 6.4MB
    unsigned short* meanh = (unsigned short*)(ws + o); o += (size_t)N_NODES * IN_CH * 2;
    unsigned short* Wc = (unsigned short*)(ws + o); o += (size_t)HID * 2 * IN_CH * 2;  // 32KB

    // no memsets: prep zeroes gmax/gcursor; edgesP writes are count-guarded;
    // meanh/xh/xh8/Wc fully overwritten every call.

    prep_k<<<XCAST_BLOCKS + WPREP_BLOCKS + ZERO_BLOCKS, 256, 0, stream>>>(
        x, W_l, W_r, xh, xh8, Wc, zbase);
    part_k<<<PART_BLOCKS, 512, 0, stream>>>(ei, gcursor, edgesP);
    meanp_k<<<NPART, 512, 0, stream>>>(xh8, gcursor, edgesP, meanh);
    gemm_pool_k<<<(N_NODES + 2 * MBLK - 1) / (2 * MBLK), 512, 0, stream>>>(
        xh, meanh, Wc, b_l, batch, gmax);
    head_k<<<1, 256, 0, stream>>>(gmax, W_lin, b_lin, out);
}

// Round 16
// 66.868 us; speedup vs baseline: 1.0200x; 1.0200x over previous
//
#include <hip/hip_runtime.h>
#include <hip/hip_fp8.h>

#define N_NODES 100000
#define N_EDGES 1250000
#define IN_CH 64
#define HID 128
#define OUT_CH 2
#define NUM_GRAPHS 128

#define PSHIFT 8
#define PSIZE 256                               // nodes per partition
#define NPART ((N_NODES + PSIZE - 1) / PSIZE)   // 391
#define MAXE 4096   // capacity per partition region (mean 3197, sigma 56 -> 16-sigma)
#define TILE 8192   // edges per part_k block
#define PART_BLOCKS ((N_EDGES + TILE - 1) / TILE)  // 153

typedef _Float16 half2v __attribute__((ext_vector_type(2)));
typedef _Float16 half8 __attribute__((ext_vector_type(8)));
typedef float f32x4 __attribute__((ext_vector_type(4)));
typedef float f32x2 __attribute__((ext_vector_type(2)));

#define AS1 __attribute__((address_space(1)))
#define AS3 __attribute__((address_space(3)))

#define XCAST_BLOCKS (N_NODES * IN_CH / 4 / 512)  // 3125 (2 consecutive float4/thread)
#define WPREP_BLOCKS 64
#define ZERO_BLOCKS 16
// zero region (u32 words): gmax | gcursor
#define ZW_GMAX (NUM_GRAPHS * HID)  // 16384
#define ZW_CUR 512
#define ZWORDS (ZW_GMAX + ZW_CUR)

__device__ __forceinline__ unsigned pkh2(float a, float b) {
    half2v h;
    h[0] = (_Float16)a;
    h[1] = (_Float16)b;
    return __builtin_bit_cast(unsigned, h);
}

// ---- fp8 e4m3 pack/unpack (HW cvt on gfx950; header-type fallback) --------
__device__ __forceinline__ unsigned pk_fp8x4(float a, float b, float c, float d) {
#if __has_builtin(__builtin_amdgcn_cvt_pk_fp8_f32)
    int r = __builtin_amdgcn_cvt_pk_fp8_f32(a, b, 0, false);
    r = __builtin_amdgcn_cvt_pk_fp8_f32(c, d, r, true);
    return (unsigned)r;
#else
    __hip_fp8_e4m3 qa(a), qb(b), qc(c), qd(d);
    return (unsigned)qa.__x | ((unsigned)qb.__x << 8) | ((unsigned)qc.__x << 16) |
           ((unsigned)qd.__x << 24);
#endif
}

__device__ __forceinline__ void dec_fp8x4(float* a, unsigned u) {
#if __has_builtin(__builtin_amdgcn_cvt_pk_f32_fp8)
    const f32x2 lo = __builtin_amdgcn_cvt_pk_f32_fp8((int)u, false);
    const f32x2 hi = __builtin_amdgcn_cvt_pk_f32_fp8((int)u, true);
    a[0] += lo[0]; a[1] += lo[1]; a[2] += hi[0]; a[3] += hi[1];
#else
    __hip_fp8_e4m3 t0, t1, t2, t3;
    t0.__x = (unsigned char)u;
    t1.__x = (unsigned char)(u >> 8);
    t2.__x = (unsigned char)(u >> 16);
    t3.__x = (unsigned char)(u >> 24);
    a[0] += (float)t0; a[1] += (float)t1; a[2] += (float)t2; a[3] += (float)t3;
#endif
}

__device__ __forceinline__ void acc16p8(float* a, uint4 v) {
    dec_fp8x4(a + 0, v.x);
    dec_fp8x4(a + 4, v.y);
    dec_fp8x4(a + 8, v.z);
    dec_fp8x4(a + 12, v.w);
}

// ---------------------------------------------------------------------------
// K1 prep: [0,XCAST) x -> {f16, fp8}; [XCAST,+WPREP) weight prep;
// [+WPREP,+ZERO) zero gmax/gcursor. No histogram pass.
// ---------------------------------------------------------------------------
__global__ __launch_bounds__(256) void prep_k(const float* __restrict__ x,
                                              const float* __restrict__ W_l,
                                              const float* __restrict__ W_r,
                                              unsigned short* __restrict__ xh,
                                              unsigned char* __restrict__ xh8,
                                              unsigned short* __restrict__ Wc,
                                              unsigned* __restrict__ zbase) {
    const int b = (int)blockIdx.x;
    const int tid = (int)threadIdx.x;
    if (b < XCAST_BLOCKS) {
        const int u0 = (b * 256 + tid) * 2;  // 2 consecutive float4 units
        const float4 v0 = reinterpret_cast<const float4*>(x)[u0];
        const float4 v1 = reinterpret_cast<const float4*>(x)[u0 + 1];
        uint4 hf;
        hf.x = pkh2(v0.x, v0.y);
        hf.y = pkh2(v0.z, v0.w);
        hf.z = pkh2(v1.x, v1.y);
        hf.w = pkh2(v1.z, v1.w);
        reinterpret_cast<uint4*>(xh)[u0 >> 1] = hf;
        uint2 q;
        q.x = pk_fp8x4(v0.x, v0.y, v0.z, v0.w);
        q.y = pk_fp8x4(v1.x, v1.y, v1.z, v1.w);
        reinterpret_cast<uint2*>(xh8)[u0 >> 1] = q;
        return;
    }
    const int b2 = b - XCAST_BLOCKS;
    if (b2 < WPREP_BLOCKS) {
        const int i = b2 * 256 + tid;
        if (i < HID * 2 * IN_CH) {
            const int o = i >> 7;
            const int k = i & 127;
            const float v = (k < IN_CH) ? W_l[o * IN_CH + k] : W_r[o * IN_CH + (k - IN_CH)];
            const _Float16 h = (_Float16)v;
            Wc[i] = __builtin_bit_cast(unsigned short, h);
        }
        return;
    }
    const int z = b2 - WPREP_BLOCKS;  // 0..ZERO_BLOCKS-1
    for (int i = z * 256 + tid; i < ZWORDS; i += ZERO_BLOCKS * 256) zbase[i] = 0u;
}

// ---------------------------------------------------------------------------
// K2 part: single-pass bucketing into fixed-capacity partition regions.
// TILE=8192 (16 edges/thread). Shfl-based block scan (2 barriers, no LDS
// ping-pong). One atomicAdd per (block,bin) -> contiguous runs of packed u32.
// ---------------------------------------------------------------------------
__global__ __launch_bounds__(512) void part_k(const int* __restrict__ ei,
                                              unsigned* __restrict__ gcursor,
                                              unsigned* __restrict__ edgesP) {
    __shared__ int lhist[512];
    __shared__ int lpre[512];
    __shared__ int gbase[512];
    __shared__ unsigned stage[TILE];        // 32KB
    __shared__ unsigned short sbin[TILE];   // 16KB
    __shared__ int wsum[8], wpre[8];

    const int tid = (int)threadIdx.x;
    const int lane = tid & 63;
    const int wv = tid >> 6;
    const int e0 = (int)blockIdx.x * TILE;
    const int nv = min(TILE, N_EDGES - e0);

    lhist[tid] = 0;
    __syncthreads();

    int esrc[16], emeta[16];
#pragma unroll
    for (int k = 0; k < 16; ++k) {
        const int e = e0 + k * 512 + tid;
        emeta[k] = -1;
        if (e < N_EDGES) {
            esrc[k] = ei[e];
            const int dst = ei[N_EDGES + e];
            const int bin = dst >> PSHIFT;               // 9 bits (<512)
            const int dl = dst & (PSIZE - 1);            // 8 bits
            const int rank = atomicAdd(&lhist[bin], 1);  // <8192: 13 bits
            emeta[k] = bin | (dl << 9) | (rank << 17);
        }
    }
    __syncthreads();

    // block-local exclusive scan: per-wave shfl inclusive + cross-wave fixup
    const int v = lhist[tid];
    int s = v;
#pragma unroll
    for (int o = 1; o < 64; o <<= 1) {
        const int t = __shfl_up(s, o, 64);
        if (lane >= o) s += t;
    }
    if (lane == 63) wsum[wv] = s;
    __syncthreads();
    if (wv == 0) {
        const int ws = (lane < 8) ? wsum[lane] : 0;
        int p = ws;
#pragma unroll
        for (int o = 1; o < 8; o <<= 1) {
            const int t = __shfl_up(p, o, 64);
            if (lane >= o) p += t;
        }
        if (lane < 8) wpre[lane] = p - ws;
    }
    __syncthreads();
    lpre[tid] = (s - v) + wpre[wv];
    if (tid < NPART) gbase[tid] = v ? (int)atomicAdd(&gcursor[tid], (unsigned)v) : 0;
    __syncthreads();

#pragma unroll
    for (int k = 0; k < 16; ++k) {
        if (emeta[k] >= 0) {
            const int bin = emeta[k] & 511;
            const int dl = (emeta[k] >> 9) & 255;
            const int rank = emeta[k] >> 17;
            const int pos = lpre[bin] + rank;
            stage[pos] = (unsigned)esrc[k] | ((unsigned)dl << 17);
            sbin[pos] = (unsigned short)bin;
        }
    }
    __syncthreads();

    for (int i = tid; i < nv; i += 512) {
        const int b = sbin[i];
        const int pos = gbase[b] + (i - lpre[b]);
        if (pos < MAXE) edgesP[(size_t)b * MAXE + pos] = stage[i];
    }
}

// ---------------------------------------------------------------------------
// K3 meanp: one block per 256-node partition. Packed edge words read ONCE
// into regs; per-dst CSR in LDS; 2 threads/dst gather fp8 rows (2x16B/row,
// 4-row unroll = 8 loads in flight). f32 accumulate, f16 out. (R10-verified)
// ---------------------------------------------------------------------------
__global__ __launch_bounds__(512) void meanp_k(const unsigned char* __restrict__ xh8,
                                               const unsigned* __restrict__ gcursor,
                                               const unsigned* __restrict__ edgesP,
                                               unsigned short* __restrict__ meanh) {
    __shared__ int ss[MAXE];               // 16KB sorted srcs
    __shared__ unsigned char dl8[MAXE];    // 4KB
    __shared__ unsigned char rk8[MAXE];    // 4KB
    __shared__ int histL[PSIZE];
    __shared__ int rowp[PSIZE];
    __shared__ int sb[2][PSIZE];

    const int tid = (int)threadIdx.x;
    const int p = (int)blockIdx.x;
    const int node0 = p << PSHIFT;
    const size_t e0 = (size_t)p * MAXE;
    const int m = min((int)gcursor[p], MAXE);

    if (tid < PSIZE) histL[tid] = 0;
    __syncthreads();

    // pass 1: read edge word once (cached in regs), local-dst + rank
    unsigned er[8];
    {
        int k = 0;
        for (int i = tid; i < m; i += 512, ++k) {
            const unsigned pr = edgesP[e0 + i];
            er[k] = pr;
            const int d = (int)((pr >> 17) & 255u);
            dl8[i] = (unsigned char)d;
            rk8[i] = (unsigned char)atomicAdd(&histL[d], 1);
        }
    }
    __syncthreads();

    if (tid < PSIZE) sb[0][tid] = histL[tid];
    __syncthreads();
    int pb = 0;
    for (int o = 1; o < PSIZE; o <<= 1) {
        if (tid < PSIZE)
            sb[pb ^ 1][tid] = sb[pb][tid] + ((tid >= o) ? sb[pb][tid - o] : 0);
        pb ^= 1;
        __syncthreads();
    }
    if (tid < PSIZE) rowp[tid] = sb[pb][tid] - histL[tid];
    __syncthreads();

    // pass 2: scatter srcs into per-dst runs (LDS only; edge word from regs)
    {
        int k = 0;
        for (int i = tid; i < m; i += 512, ++k)
            ss[rowp[dl8[i]] + rk8[i]] = (int)(er[k] & 0x1FFFFu);
    }
    __syncthreads();

    const int owner = tid >> 1;
    const int half = tid & 1;
    const int node = node0 + owner;
    if (node >= N_NODES) return;

    const int deg = histL[owner];
    const int base = rowp[owner];

    float acc[32];
#pragma unroll
    for (int i = 0; i < 32; ++i) acc[i] = 0.f;

    int j = 0;
    for (; j + 4 <= deg; j += 4) {
        const int s0 = ss[base + j];
        const int s1 = ss[base + j + 1];
        const int s2 = ss[base + j + 2];
        const int s3 = ss[base + j + 3];
        const uint4* r0 = reinterpret_cast<const uint4*>(xh8 + (size_t)s0 * IN_CH + half * 32);
        const uint4* r1 = reinterpret_cast<const uint4*>(xh8 + (size_t)s1 * IN_CH + half * 32);
        const uint4* r2 = reinterpret_cast<const uint4*>(xh8 + (size_t)s2 * IN_CH + half * 32);
        const uint4* r3 = reinterpret_cast<const uint4*>(xh8 + (size_t)s3 * IN_CH + half * 32);
        const uint4 a0 = r0[0], a1 = r0[1];
        const uint4 b0 = r1[0], b1 = r1[1];
        const uint4 c0 = r2[0], c1 = r2[1];
        const uint4 d0 = r3[0], d1 = r3[1];
        acc16p8(acc + 0, a0); acc16p8(acc + 16, a1);
        acc16p8(acc + 0, b0); acc16p8(acc + 16, b1);
        acc16p8(acc + 0, c0); acc16p8(acc + 16, c1);
        acc16p8(acc + 0, d0); acc16p8(acc + 16, d1);
    }
    for (; j < deg; ++j) {
        const int s0 = ss[base + j];
        const uint4* r0 = reinterpret_cast<const uint4*>(xh8 + (size_t)s0 * IN_CH + half * 32);
        const uint4 a0 = r0[0], a1 = r0[1];
        acc16p8(acc + 0, a0); acc16p8(acc + 16, a1);
    }

    const float rcp = 1.0f / fmaxf((float)deg, 1.0f);
    uint4 ov[4];
#pragma unroll
    for (int c = 0; c < 4; ++c) {
        ov[c].x = pkh2(acc[c * 8 + 0] * rcp, acc[c * 8 + 1] * rcp);
        ov[c].y = pkh2(acc[c * 8 + 2] * rcp, acc[c * 8 + 3] * rcp);
        ov[c].z = pkh2(acc[c * 8 + 4] * rcp, acc[c * 8 + 5] * rcp);
        ov[c].w = pkh2(acc[c * 8 + 6] * rcp, acc[c * 8 + 7] * rcp);
    }
    uint4* op = reinterpret_cast<uint4*>(meanh + (size_t)node * IN_CH + half * 32);
#pragma unroll
    for (int c = 0; c < 4; ++c) op[c] = ov[c];
}

// ---------------------------------------------------------------------------
// K4: MFMA GEMM + relu + per-graph max pool. TWO 128-node tiles per block.
// Staging via global_load_lds (async, width=16): linear LDS dest + inverse-
// swizzled per-lane global source (rule #21; XOR involution preserves the
// swizzled ds_read). Partial tail sub-tile falls back to scalar staging.
// ---------------------------------------------------------------------------
#define MBLK 128

__device__ __forceinline__ void flushmax(unsigned* lmax, unsigned int* gmax,
                                         int g, int gbase, int l15,
                                         const float* rmax) {
    const int slot = g - gbase;
    if (slot < 4) {
#pragma unroll
        for (int nt = 0; nt < 8; ++nt)
            atomicMax(&lmax[slot * HID + nt * 16 + l15], __float_as_uint(rmax[nt]));
    } else {
#pragma unroll
        for (int nt = 0; nt < 8; ++nt)
            atomicMax(&gmax[(size_t)g * HID + nt * 16 + l15], __float_as_uint(rmax[nt]));
    }
}

__global__ __launch_bounds__(512) void gemm_pool_k(const unsigned short* __restrict__ xh,
                                                   const unsigned short* __restrict__ meanh,
                                                   const unsigned short* __restrict__ Wc,
                                                   const float* __restrict__ b_l,
                                                   const int* __restrict__ batch,
                                                   unsigned int* __restrict__ gmax) {
    __shared__ uint4 fe[MBLK * 16];
    __shared__ uint4 wt[HID * 16];
    __shared__ unsigned lmax[4 * HID];
    __shared__ int bt[MBLK];

    const int tid = (int)threadIdx.x;
    const int lane = tid & 63;
    const int w = tid >> 6;
    const int l15 = lane & 15, q = lane >> 4;

    // weights: async stage once, reused by both sub-tiles.
    // slot id = tid + t*512; lanes of a wave cover consecutive slots ->
    // wave-uniform LDS base &wt[w*64 + t*512], lane writes base+lane*16.
#pragma unroll
    for (int t = 0; t < 4; ++t) {
        const int id = tid + t * 512;
        const int row = id >> 4, cs = id & 15;
        const int c = cs ^ (row & 7);  // inverse swizzle on the SOURCE
        __builtin_amdgcn_global_load_lds(
            (const AS1 unsigned*)(reinterpret_cast<const uint4*>(Wc) + (row * 16 + c)),
            (AS3 unsigned*)&wt[w * 64 + t * 512], 16, 0, 0);
    }

    float bias[8];
#pragma unroll
    for (int nt = 0; nt < 8; ++nt) bias[nt] = b_l[nt * 16 + l15];

#pragma unroll 1
    for (int sub = 0; sub < 2; ++sub) {
        const int nb = (int)blockIdx.x * (2 * MBLK) + sub * MBLK;
        if (nb >= N_NODES) break;
        const int nvalid = min(MBLK, N_NODES - nb);

        if (nvalid == MBLK) {
            // async staging: feature chunks c<8 from meanh, c>=8 from xh
#pragma unroll
            for (int t = 0; t < 4; ++t) {
                const int id = tid + t * 512;
                const int row = id >> 4, cs = id & 15;
                const int c = cs ^ (row & 7);
                const int n = nb + row;
                const uint4* src = (c < 8)
                    ? (reinterpret_cast<const uint4*>(meanh) + ((size_t)n * 8 + c))
                    : (reinterpret_cast<const uint4*>(xh) + ((size_t)n * 8 + (c - 8)));
                __builtin_amdgcn_global_load_lds(
                    (const AS1 unsigned*)src,
                    (AS3 unsigned*)&fe[w * 64 + t * 512], 16, 0, 0);
            }
        } else {
            // scalar tail path (exactly one sub-tile in the whole grid)
#pragma unroll
            for (int t = 0; t < 4; ++t) {
                const int id = tid + t * 512;
                const int row = id >> 4, c = id & 15;
                const int n = nb + row;
                uint4 v = make_uint4(0u, 0u, 0u, 0u);
                if (n < N_NODES) {
                    v = (c < 8) ? reinterpret_cast<const uint4*>(meanh)[(size_t)n * 8 + c]
                                : reinterpret_cast<const uint4*>(xh)[(size_t)n * 8 + (c - 8)];
                }
                fe[row * 16 + (c ^ (row & 7))] = v;
            }
        }
        if (tid < MBLK) bt[tid] = (nb + tid < N_NODES) ? batch[nb + tid] : -1;
        lmax[tid] = 0u;  // 4*HID == 512
        __syncthreads();  // drains vmcnt -> async LDS writes complete

        f32x4 acc[8];
#pragma unroll
        for (int nt = 0; nt < 8; ++nt) acc[nt] = (f32x4){0.f, 0.f, 0.f, 0.f};

        const int arow = w * 16 + l15;
#pragma unroll
        for (int kb = 0; kb < 4; ++kb) {
            const int ac = kb * 4 + q;
            const half8 a = __builtin_bit_cast(half8, fe[arow * 16 + (ac ^ (arow & 7))]);
#pragma unroll
            for (int nt = 0; nt < 8; ++nt) {
                const int nrow = nt * 16 + l15;
                const half8 b = __builtin_bit_cast(half8, wt[nrow * 16 + (ac ^ (nrow & 7))]);
                acc[nt] = __builtin_amdgcn_mfma_f32_16x16x32_f16(a, b, acc[nt], 0, 0, 0);
            }
        }

        const int gbase = bt[0];
        const int rowb = w * 16 + q * 4;
        int curg = -1;
        float rmax[8];
#pragma unroll
        for (int nt = 0; nt < 8; ++nt) rmax[nt] = 0.f;

#pragma unroll
        for (int reg = 0; reg < 4; ++reg) {
            const int g = bt[rowb + reg];
            if (g >= 0) {
                float h[8];
#pragma unroll
                for (int nt = 0; nt < 8; ++nt) h[nt] = fmaxf(acc[nt][reg] + bias[nt], 0.f);
                if (g != curg) {
                    if (curg >= 0) flushmax(lmax, gmax, curg, gbase, l15, rmax);
                    curg = g;
#pragma unroll
                    for (int nt = 0; nt < 8; ++nt) rmax[nt] = h[nt];
                } else {
#pragma unroll
                    for (int nt = 0; nt < 8; ++nt) rmax[nt] = fmaxf(rmax[nt], h[nt]);
                }
            }
        }
        if (curg >= 0) flushmax(lmax, gmax, curg, gbase, l15, rmax);
        __syncthreads();

        int span = bt[nvalid - 1] - gbase + 1;
        if (span > 4) span = 4;
        if (tid < span * HID) {
            const unsigned v = lmax[tid];
            if (v) atomicMax(&gmax[(size_t)(gbase + (tid >> 7)) * HID + (tid & 127)], v);
        }
        __syncthreads();  // lmax/fe reads complete before next sub re-stages
    }
}

// ---------------------------------------------------------------------------
// K5: head. out[g][oc] = gmax[g].W_lin[oc] + b_lin[oc]  (float4 dot)
// ---------------------------------------------------------------------------
__global__ __launch_bounds__(256) void head_k(const unsigned int* __restrict__ gmax_u,
                                              const float* __restrict__ W_lin,
                                              const float* __restrict__ b_lin,
                                              float* __restrict__ out) {
    const int t = (int)threadIdx.x;
    const int g = t >> 1;
    const int oc = t & 1;
    const float4* gr = reinterpret_cast<const float4*>((const float*)gmax_u + (size_t)g * HID);
    const float4* wr = reinterpret_cast<const float4*>(W_lin + oc * HID);
    float acc = b_lin[oc];
#pragma unroll 8
    for (int k = 0; k < HID / 4; ++k) {
        const float4 a = gr[k];
        const float4 w = wr[k];
        acc += a.x * w.x + a.y * w.y + a.z * w.z + a.w * w.w;
    }
    out[(size_t)g * OUT_CH + oc] = acc;
}

extern "C" void kernel_launch(void* const* d_in, const int* in_sizes, int n_in,
                              void* d_out, int out_size, void* d_ws, size_t ws_size,
                              hipStream_t stream) {
    const float* x = (const float*)d_in[0];
    const float* W_l = (const float*)d_in[1];
    const float* b_l = (const float*)d_in[2];
    const float* W_r = (const float*)d_in[3];
    const float* W_lin = (const float*)d_in[4];
    const float* b_lin = (const float*)d_in[5];
    const int* ei = (const int*)d_in[6];
    const int* batch = (const int*)d_in[7];
    float* out = (float*)d_out;

    char* ws = (char*)d_ws;
    size_t o = 0;
    unsigned* zbase = (unsigned*)(ws + o);  // gmax | gcursor (zeroed by prep)
    unsigned int* gmax = zbase;
    unsigned* gcursor = zbase + ZW_GMAX;
    o += (size_t)ZWORDS * 4;
    o = (o + 255) & ~(size_t)255;
    unsigned* edgesP = (unsigned*)(ws + o); o += (size_t)NPART * MAXE * 4;             // 6.4MB
    unsigned short* xh = (unsigned short*)(ws + o); o += (size_t)N_NODES * IN_CH * 2;  // 12.8MB
    unsigned char* xh8 = (unsigned char*)(ws + o); o += (size_t)N_NODES * IN_CH;       // 6.4MB
    unsigned short* meanh = (unsigned short*)(ws + o); o += (size_t)N_NODES * IN_CH * 2;
    unsigned short* Wc = (unsigned short*)(ws + o); o += (size_t)HID * 2 * IN_CH * 2;  // 32KB

    // no memsets: prep zeroes gmax/gcursor; edgesP writes are count-guarded;
    // meanh/xh/xh8/Wc fully overwritten every call.

    prep_k<<<XCAST_BLOCKS + WPREP_BLOCKS + ZERO_BLOCKS, 256, 0, stream>>>(
        x, W_l, W_r, xh, xh8, Wc, zbase);
    part_k<<<PART_BLOCKS, 512, 0, stream>>>(ei, gcursor, edgesP);
    meanp_k<<<NPART, 512, 0, stream>>>(xh8, gcursor, edgesP, meanh);
    gemm_pool_k<<<(N_NODES + 2 * MBLK - 1) / (2 * MBLK), 512, 0, stream>>>(
        xh, meanh, Wc, b_l, batch, gmax);
    head_k<<<1, 256, 0, stream>>>(gmax, W_lin, b_lin, out);
}